// Round 9
// baseline (115.019 us; speedup 1.0000x reference)
//
#include <hip/hip_runtime.h>

// WaveletNet lifting: P/U filters are length-1 => scalar multiplies.
// x: (B, L) fp32 -> z: (B, 2, L/2) fp32, plus scalar log_det=0 at out[B*L].
//
// Each thread handles 16 consecutive floats (8 even/odd pairs):
//   4x global_load_dwordx4 issued back-to-back (4 outstanding loads/thread
//   for latency hiding), then 4x nontemporal global_store_dwordx4 out
//   (2 to the evens half-row, 2 to the odds half-row).
//
// Evidence from round 6 rocprof: kernel dispatch < 41.8 us (absent from
// top-5; harness poison fills at ~42 us each dominate the timed graph).
// This round tests whether the kernel is MLP/latency-limited (should drop
// toward the ~21 us traffic floor) or already BW-bound (headline unchanged).

#define BB 256
#define LL 65536
#define HH (LL / 2)              // 32768 pairs per row
#define NSTEPS 4

typedef float f32x4 __attribute__((ext_vector_type(4)));

__global__ __launch_bounds__(256) void wavelet_lift_kernel(
    const f32x4* __restrict__ x4,    // B*L/4 vec4s: (e,o,e,o)
    const float* __restrict__ P,     // 4 coeffs (N_STEPS x 1)
    const float* __restrict__ U,     // 4 coeffs
    f32x4* __restrict__ out4,        // B*2*H floats viewed as vec4
    float* __restrict__ out)         // for log_det at [B*L]
{
    const int t = blockIdx.x * blockDim.x + threadIdx.x;  // 0 .. B*L/16-1

    // Issue all 4 loads before any dependent compute (4 in flight).
    const f32x4 va = x4[4 * t + 0];
    const f32x4 vb = x4[4 * t + 1];
    const f32x4 vc = x4[4 * t + 2];
    const f32x4 vd = x4[4 * t + 3];

    const float p0 = P[0], p1 = P[1], p2 = P[2], p3 = P[3];
    const float u0 = U[0], u1 = U[1], u2 = U[2], u3 = U[3];

    float e[8] = {va.x, va.z, vb.x, vb.z, vc.x, vc.z, vd.x, vd.z};
    float o[8] = {va.y, va.w, vb.y, vb.w, vc.y, vc.w, vd.y, vd.w};

#pragma unroll
    for (int j = 0; j < 8; ++j) {
        float ee = e[j], oo = o[j], d;
        d = oo - p0 * ee; ee = ee + u0 * d; oo = d;
        d = oo - p1 * ee; ee = ee + u1 * d; oo = d;
        d = oo - p2 * ee; ee = ee + u2 * d; oo = d;
        d = oo - p3 * ee; ee = ee + u3 * d; oo = d;
        e[j] = ee; o[j] = oo;
    }

    // Output layout: z[b][0][i] (evens, H floats) then z[b][1][i] (odds).
    // One row = 2*H floats = 2*H/4 vec4s. Threads per row = H/8 = 4096.
    const int b = t >> 12;               // t / 4096
    const int q = (t & 4095) * 2;        // vec4 index within evens half-row
    f32x4* rowE = out4 + (size_t)b * (2 * HH / 4) + q;
    f32x4* rowO = rowE + (HH / 4);       // + H floats

    f32x4 ve0 = {e[0], e[1], e[2], e[3]};
    f32x4 ve1 = {e[4], e[5], e[6], e[7]};
    f32x4 vo0 = {o[0], o[1], o[2], o[3]};
    f32x4 vo1 = {o[4], o[5], o[6], o[7]};
    __builtin_nontemporal_store(ve0, rowE + 0);
    __builtin_nontemporal_store(ve1, rowE + 1);
    __builtin_nontemporal_store(vo0, rowO + 0);
    __builtin_nontemporal_store(vo1, rowO + 1);

    if (t == 0) {
        out[(size_t)BB * LL] = 0.0f;     // log_det
    }
}

extern "C" void kernel_launch(void* const* d_in, const int* in_sizes, int n_in,
                              void* d_out, int out_size, void* d_ws, size_t ws_size,
                              hipStream_t stream) {
    const f32x4* x4 = (const f32x4*)d_in[0];
    const float* P = (const float*)d_in[1];
    const float* U = (const float*)d_in[2];
    f32x4* out4 = (f32x4*)d_out;
    float* out = (float*)d_out;

    const int total_threads = BB * LL / 16;  // 1,048,576
    const int block = 256;
    const int grid = total_threads / block;  // 4096

    wavelet_lift_kernel<<<grid, block, 0, stream>>>(x4, P, U, out4, out);
}

// Round 13
// 110.514 us; speedup vs baseline: 1.0408x; 1.0408x over previous
//
#include <hip/hip_runtime.h>

// WaveletNet lifting: P/U filters are length-1 => scalar multiplies.
// x: (B, L) fp32 -> z: (B, 2, L/2) fp32, plus scalar log_det=0 at out[B*L].
//
// BEST MEASURED CONFIG (round 6: 109.6 us headline). Each thread handles
// 8 consecutive floats (4 even/odd pairs): 2x global_load_dwordx4 in
// (32 B lane stride), 2x nontemporal global_store_dwordx4 out, each store
// instruction covering a dense wave-contiguous 1 KiB span.
//
// Measured tradeoff history:
//  - dense 16B loads + 8B stores       : 113.3 us (prior session)
//  - this layout (mixed)               : 109.6 us (round 6)
//  - 16 float/thread, strided stores   : 115.0 us (round 9 regression)
// Harness envelope: ~86 us of 256 MiB poison fills at ~6.3 TB/s dominate
// the timed graph; kernel itself ~25-26 us vs 21.3 us traffic floor (84%
// of achievable BW).

#define BB 256
#define LL 65536
#define HH (LL / 2)              // 32768 pairs per row
#define QROW (HH / 4)            // 8192 vec4 output chunks per half-row
#define NSTEPS 4

typedef float f32x4 __attribute__((ext_vector_type(4)));

__global__ __launch_bounds__(256) void wavelet_lift_kernel(
    const f32x4* __restrict__ x4,    // B*L/4 vec4s: (e,o,e,o)
    const float* __restrict__ P,     // 4 coeffs (N_STEPS x 1)
    const float* __restrict__ U,     // 4 coeffs
    f32x4* __restrict__ out4,        // B*2*H floats viewed as vec4
    float* __restrict__ out)         // for log_det at [B*L]
{
    const int t = blockIdx.x * blockDim.x + threadIdx.x;  // 0 .. B*L/8-1

    const float p0 = P[0], p1 = P[1], p2 = P[2], p3 = P[3];
    const float u0 = U[0], u1 = U[1], u2 = U[2], u3 = U[3];

    const f32x4 va = x4[2 * t];
    const f32x4 vb = x4[2 * t + 1];

    float e[4] = {va.x, va.z, vb.x, vb.z};
    float o[4] = {va.y, va.w, vb.y, vb.w};

#pragma unroll
    for (int j = 0; j < 4; ++j) {
        float ee = e[j], oo = o[j], d;
        d = oo - p0 * ee; ee = ee + u0 * d; oo = d;
        d = oo - p1 * ee; ee = ee + u1 * d; oo = d;
        d = oo - p2 * ee; ee = ee + u2 * d; oo = d;
        d = oo - p3 * ee; ee = ee + u3 * d; oo = d;
        e[j] = ee; o[j] = oo;
    }

    // Output layout: z[b][0][i] (evens) then z[b][1][i] (odds), H floats each.
    // One row = 2*H floats = 2*H/4 vec4s.
    const int b = t >> 13;               // t / QROW
    const int q = t & (QROW - 1);        // vec4 index within half-row
    f32x4* rowE = out4 + (size_t)b * (2 * HH / 4) + q;
    f32x4* rowO = rowE + QROW;           // + H floats

    f32x4 ve = {e[0], e[1], e[2], e[3]};
    f32x4 vo = {o[0], o[1], o[2], o[3]};
    __builtin_nontemporal_store(ve, rowE);
    __builtin_nontemporal_store(vo, rowO);

    if (t == 0) {
        out[(size_t)BB * LL] = 0.0f;     // log_det
    }
}

extern "C" void kernel_launch(void* const* d_in, const int* in_sizes, int n_in,
                              void* d_out, int out_size, void* d_ws, size_t ws_size,
                              hipStream_t stream) {
    const f32x4* x4 = (const f32x4*)d_in[0];
    const float* P = (const float*)d_in[1];
    const float* U = (const float*)d_in[2];
    f32x4* out4 = (f32x4*)d_out;
    float* out = (float*)d_out;

    const int total_threads = BB * LL / 8;   // 2,097,152
    const int block = 256;
    const int grid = total_threads / block;  // 8192

    wavelet_lift_kernel<<<grid, block, 0, stream>>>(x4, P, U, out4, out);
}

// Round 15
// 110.177 us; speedup vs baseline: 1.0440x; 1.0031x over previous
//
#include <hip/hip_runtime.h>

// WaveletNet lifting: P/U filters are length-1 => scalar multiplies.
// x: (B, L) fp32 -> z: (B, 2, L/2) fp32, plus scalar log_det=0 at out[B*L].
//
// Round-14 experiment: make BOTH global sides per-instruction dense.
//  - dense loads: lane-linear vec4 (each load instr = contiguous 1 KiB/wave)
//  - lift in registers
//  - wave-private LDS deinterleave (no barrier: same wave writes+reads,
//    DS ops ordered via lgkmcnt): 4x ds_write_b64 + 2x ds_read_b128,
//    both at 2-way bank aliasing = conflict-free on CDNA4 (m136)
//  - dense nontemporal stores (each store instr = contiguous 1 KiB/wave)
//
// History: 113.3 (dense loads + 8B stores) / 109.6 (strided loads + dense
// stores, best) / 115.0 (16f/thread strided stores). Kernel est ~24.5 us vs
// 21.3 us float4-copy floor; this tests whether strided-load line-splitting
// (16 lines/instr vs 8) is the residual.

#define BB 256
#define LL 65536
#define HH (LL / 2)              // 32768 pairs per row; evens vec4s/row = 8192

typedef float f32x4 __attribute__((ext_vector_type(4)));
typedef float f32x2 __attribute__((ext_vector_type(2)));

__global__ __launch_bounds__(256) void wavelet_lift_kernel(
    const f32x4* __restrict__ x4,    // B*L/4 vec4s: (e,o,e,o)
    const float* __restrict__ P,     // 4 coeffs
    const float* __restrict__ U,     // 4 coeffs
    f32x4* __restrict__ out4,        // B*2*H floats viewed as vec4
    float* __restrict__ out)         // log_det at [B*L]
{
    // Per-wave private 2 KiB region: evens float2[128] then odds float2[128].
    __shared__ float lds[4][512];

    const int w    = threadIdx.x >> 6;
    const int lane = threadIdx.x & 63;
    const int wgid = blockIdx.x * 4 + w;     // global wave id, 0..32767
    const int wb   = wgid * 128;             // first input vec4 of this wave

    // Dense loads: instr A covers vec4s [wb, wb+64), instr B [wb+64, wb+128).
    const f32x4 va = x4[wb + lane];
    const f32x4 vb = x4[wb + 64 + lane];

    const float p0 = P[0], p1 = P[1], p2 = P[2], p3 = P[3];
    const float u0 = U[0], u1 = U[1], u2 = U[2], u3 = U[3];

    float e[4] = {va.x, va.z, vb.x, vb.z};
    float o[4] = {va.y, va.w, vb.y, vb.w};

#pragma unroll
    for (int j = 0; j < 4; ++j) {
        float ee = e[j], oo = o[j], d;
        d = oo - p0 * ee; ee = ee + u0 * d; oo = d;
        d = oo - p1 * ee; ee = ee + u1 * d; oo = d;
        d = oo - p2 * ee; ee = ee + u2 * d; oo = d;
        d = oo - p3 * ee; ee = ee + u3 * d; oo = d;
        e[j] = ee; o[j] = oo;
    }

    // Deinterleave via wave-private LDS.
    // Slot s (float2) = evens (resp. odds) of input vec4 (wb + s).
    f32x2* ev = (f32x2*)&lds[w][0];
    f32x2* od = (f32x2*)&lds[w][256];
    ev[lane]      = (f32x2){e[0], e[1]};     // from vec4 wb+lane
    ev[64 + lane] = (f32x2){e[2], e[3]};     // from vec4 wb+64+lane
    od[lane]      = (f32x2){o[0], o[1]};
    od[64 + lane] = (f32x2){o[2], o[3]};

    // Same-wave readback (lgkmcnt-ordered): slots {2*lane, 2*lane+1}
    // = evens vec4 g = wb/2 + lane.
    const f32x4 ve = ((const f32x4*)ev)[lane];
    const f32x4 vo = ((const f32x4*)od)[lane];

    // Output: row b = g / 8192, q = g % 8192; row = 16384 vec4s (2*H floats).
    const int g = (wb >> 1) + lane;
    const int b = g >> 13;
    const int q = g & 8191;
    f32x4* rowE = out4 + (size_t)b * 16384 + q;
    f32x4* rowO = rowE + 8192;               // + H floats

    __builtin_nontemporal_store(ve, rowE);
    __builtin_nontemporal_store(vo, rowO);

    if (wgid == 0 && lane == 0) {
        out[(size_t)BB * LL] = 0.0f;         // log_det
    }
}

extern "C" void kernel_launch(void* const* d_in, const int* in_sizes, int n_in,
                              void* d_out, int out_size, void* d_ws, size_t ws_size,
                              hipStream_t stream) {
    const f32x4* x4 = (const f32x4*)d_in[0];
    const float* P = (const float*)d_in[1];
    const float* U = (const float*)d_in[2];
    f32x4* out4 = (f32x4*)d_out;
    float* out = (float*)d_out;

    // 32768 waves total, 4 per block.
    const int grid = 8192;
    const int block = 256;

    wavelet_lift_kernel<<<grid, block, 0, stream>>>(x4, P, U, out4, out);
}